// Round 12
// baseline (1012.003 us; speedup 1.0000x reference)
//
#include <hip/hip_runtime.h>

// Problem constants (B=8, N=4096, n_points=1024, n_samples=32, D_PTS=6, MLPS=[64,64,128])
#define NPTS  4096
#define NB    8
#define NC    1024
#define NSAMP 32
#define DP    6
#define C0    9      // 3 + D_PTS
#define C3    128
#define ROWS_TOT 262144   // NB*NC*NSAMP

// Workspace layout (bytes). Requires ws_size >= ~184 MB.
#define OFF_SS   (32ull<<10)     // 3 layers x {scale[128], shift[128]}
#define OFF_Y0   (16ull<<20)     // y0: 262144 x 64 f32 (67 MB)
#define OFF_Y1   (96ull<<20)     // y1: 262144 x 64 f32 (67 MB)
#define OFF_PSUM (168ull<<20)    // per-block channel sums   [C][NBLK]
#define OFF_PSQ  (172ull<<20)    // per-block channel sumsq  [C][NBLK]
#define OFF_GMX  (176ull<<20)    // per-centroid channel max [8192][128]
#define OFF_GMN  (180ull<<20)    // per-centroid channel min [8192][128]

typedef unsigned long long ull;

// Exact (no-FMA) squared distance to match numpy rounding; sum order ((x+y)+z).
__device__ __forceinline__ float sqdist_noc(float x, float y, float z,
                                            float cx, float cy, float cz) {
  #pragma clang fp contract(off)
  float dx = x - cx, dy = y - cy, dz = z - cz;
  return dx * dx + dy * dy + dz * dz;
}

// DPP move with old=self (masked/invalid lanes keep their value -> fmax identity)
template <int CTRL, int RM>
__device__ __forceinline__ float dpp_mov_f(float x) {
  int xi = __float_as_int(x);
  int r = __builtin_amdgcn_update_dpp(xi, xi, CTRL, RM, 0xf, false);
  return __int_as_float(r);
}

// Canonical gfx9 wave64 f32 max reduce; result valid in lane 63.
__device__ __forceinline__ float wave64_fmax(float x) {
  x = fmaxf(x, dpp_mov_f<0x111, 0xf>(x));  // row_shr:1
  x = fmaxf(x, dpp_mov_f<0x112, 0xf>(x));  // row_shr:2
  x = fmaxf(x, dpp_mov_f<0x114, 0xf>(x));  // row_shr:4
  x = fmaxf(x, dpp_mov_f<0x118, 0xf>(x));  // row_shr:8
  x = fmaxf(x, dpp_mov_f<0x142, 0xa>(x));  // row_bcast:15 -> rows 1,3
  x = fmaxf(x, dpp_mov_f<0x143, 0xc>(x));  // row_bcast:31 -> rows 2,3
  return x;
}

// ---------------------------------------------------------------------------
// FPS R12: R8 chain surgery at 512 threads (8 waves = 2 waves/SIMD, 8 pts/thr).
// R8 (256thr) measured: step=1405cyc, issue=576 (41% VALUBusy/active-CU),
// stalls=~830 exposed at 1 wave/SIMD. 8pts/thr keeps per-SIMD issue ~const
// (~150 insts/wave x 2 waves) while the co-resident wave hides the chain
// stalls. Same chain: tree argmax, f32 DPP reduce, speculative cand read,
// coords+key in the parity exchange (fold = 8-way cndmask tree, no dependent
// sxyz[last] read). 1 barrier/step. Tie-break exact (lane/wave order == index
// order, strict > prefers lower).
// ---------------------------------------------------------------------------
__global__ __launch_bounds__(512)
void fps_kernel(const float* __restrict__ xyz, float* __restrict__ cent) {
  const int b = blockIdx.x;
  const int t = threadIdx.x;                    // 0..511
  const float* X = xyz + (size_t)b * NPTS * 3;
  float* OC = cent + (size_t)b * NC * 3;

  __shared__ float4 sxyz[NPTS];                 // 64 KB
  __shared__ float4 wkc[2][8];                  // per-wave (x,y,z,key), parity-dbuf
  __shared__ alignas(16) int wki[2][8];         // per-wave winner gidx
  __shared__ int sidx[NC];                      // 4 KB

  for (int p = t; p < NPTS; p += 512)
    sxyz[p] = make_float4(X[p * 3 + 0], X[p * 3 + 1], X[p * 3 + 2], 0.f);
  __syncthreads();

  float px[8], py[8], pz[8], h[8];
  #pragma unroll
  for (int i = 0; i < 8; i++) {
    float4 v = sxyz[t * 8 + i];
    px[i] = v.x; py[i] = v.y; pz[i] = v.z;
    h[i] = fmaf(v.x, v.x, fmaf(v.y, v.y, v.z * v.z));   // |p|^2
  }

  const int wv = t >> 6;
  float4 c;   // current centroid (x,y,z,*)

  auto step_body = [&](int pw_) {
    const float c2x = c.x + c.x, c2y = c.y + c.y, c2z = c.z + c.z;
    float key[8]; int idx[8];
    #pragma unroll
    for (int i = 0; i < 8; i++) {
      key[i] = fmaf(pz[i], -c2z, fmaf(py[i], -c2y, fmaf(px[i], -c2x, h[i])));
      idx[i] = i;
    }
    #pragma unroll
    for (int s = 1; s < 8; s <<= 1) {           // tree argmax, first-max ties
      #pragma unroll
      for (int i = 0; i < 8; i += 2 * s) {
        bool tk = key[i + s] > key[i];
        key[i] = tk ? key[i + s] : key[i];
        idx[i] = tk ? idx[i + s] : idx[i];
      }
    }
    const float mx = key[0];
    const int mj = idx[0];
    float4 cand = sxyz[(t << 3) + mj];          // speculative; hides under reduce
    float wm = wave64_fmax(mx);
    float smax = __int_as_float(__builtin_amdgcn_readlane(__float_as_int(wm), 63));
    if (mx == smax) {                           // winner lane(s) of this wave
      wkc[pw_][wv] = make_float4(cand.x, cand.y, cand.z, smax);
      wki[pw_][wv] = (t << 3) + mj;
    }
  };

  // fold: best of 8 wave candidates (lower wave wins ties == lower index)
  auto fold = [&](int pr_) -> int {
    float4 q0 = wkc[pr_][0], q1 = wkc[pr_][1];
    float4 q2 = wkc[pr_][2], q3 = wkc[pr_][3];
    float4 q4 = wkc[pr_][4], q5 = wkc[pr_][5];
    float4 q6 = wkc[pr_][6], q7 = wkc[pr_][7];
    const int4 iA = *(const int4*)&wki[pr_][0];
    const int4 iB = *(const int4*)&wki[pr_][4];
    bool g1 = q1.w > q0.w; float4 a = g1 ? q1 : q0; int ia = g1 ? iA.y : iA.x;
    bool g3 = q3.w > q2.w; float4 d2 = g3 ? q3 : q2; int ib = g3 ? iA.w : iA.z;
    bool g5 = q5.w > q4.w; float4 e2 = g5 ? q5 : q4; int ic = g5 ? iB.y : iB.x;
    bool g7 = q7.w > q6.w; float4 f2 = g7 ? q7 : q6; int id = g7 ? iB.w : iB.z;
    bool gb = d2.w > a.w;  float4 u = gb ? d2 : a;  int iu = gb ? ib : ia;
    bool gd = f2.w > e2.w; float4 v = gd ? f2 : e2; int iv = gd ? id : ic;
    bool gf = v.w > u.w;   c = gf ? v : u;          return gf ? iv : iu;
  };

  // ---- iteration 1: selection 0 is point 0 (seed; t0 owns slot 0) ----
  if (t == 0) { sidx[0] = 0; h[0] = -__builtin_inff(); }
  c = sxyz[0];
  step_body(1);                                 // publish par = 1&1
  __syncthreads();

  for (int k = 2; k < NC; k++) {
    const int pr = (k - 1) & 1, pw = k & 1;
    int gidx = fold(pr);                        // selection k-1
    if (t == 0) sidx[k - 1] = gidx;
    if ((gidx >> 3) == t) {                     // retire: -INF loses everything
      int m = gidx & 7;
      #pragma unroll
      for (int i = 0; i < 8; i++)
        if (i == m) h[i] = -__builtin_inff();
    }
    step_body(pw);
    __syncthreads();
  }
  {                                             // epilogue: selection 1023
    int gidx = fold(1023 & 1);
    if (t == 0) sidx[NC - 1] = gidx;
  }
  __syncthreads();
  for (int i = t; i < NC; i += 512) {           // one-shot centroid emit
    float4 cc = sxyz[sidx[i]];
    OC[i * 3 + 0] = cc.x;
    OC[i * 3 + 1] = cc.y;
    OC[i * 3 + 2] = cc.z;
  }
}

// ---------------------------------------------------------------------------
// ball + dense0 FUSED (unchanged from R11): query_ball -> gather -> y0 + BN0
// partials; h0 never materialized.
// ---------------------------------------------------------------------------
#define BCAP 256
__global__ __launch_bounds__(256)
void ball_dense0_kernel(const float* __restrict__ xyz, const float* __restrict__ pts,
                        const float* __restrict__ cent,
                        const float* __restrict__ W0, const float* __restrict__ b0,
                        float* __restrict__ y0,
                        float* __restrict__ psum, float* __restrict__ psq) {
  const int blk = blockIdx.x;       // b*NC + c
  const int b = blk >> 10;
  const int t = threadIdx.x;
  const float* X = xyz + (size_t)b * NPTS * 3;
  const float* P = pts + (size_t)b * NPTS * DP;
  const float cx = cent[(size_t)blk * 3 + 0];
  const float cy = cent[(size_t)blk * 3 + 1];
  const float cz = cent[(size_t)blk * 3 + 2];

  __shared__ int scount;
  __shared__ ull skeys[BCAP];
  __shared__ ull ssorted[BCAP];
  __shared__ int sel[NSAMP];
  __shared__ float xs0[NSAMP * C0];
  __shared__ float w0s[C0 * 64];
  __shared__ float b0s[64];
  __shared__ float red[2][NSAMP][64];   // 16 KB
  if (t == 0) scount = 0;
  for (int e = t; e < C0 * 64; e += 256) w0s[e] = W0[e];
  if (t < 64) b0s[t] = b0[t];
  __syncthreads();

  #pragma unroll
  for (int i = 0; i < 16; i++) {
    int j = t * 16 + i;
    float sq = sqdist_noc(X[j * 3 + 0], X[j * 3 + 1], X[j * 3 + 2], cx, cy, cz);
    if (sq < 0.0017f) {                       // conservative guard
      float d = (sq > 0.f) ? sqrtf(sq) : 0.f; // exact per-reference norm
      if (d < 0.04f) {                        // strictly inside the clip value
        int pos = atomicAdd(&scount, 1);
        if (pos < BCAP)
          skeys[pos] = ((ull)(unsigned)__float_as_int(d) << 12) | (unsigned)j;
      }
    }
  }
  __syncthreads();
  const int M = min(scount, BCAP);

  if (t < M) {                                // rank-sort inner set
    ull my = skeys[t];
    int r = 0;
    for (int j2 = 0; j2 < M; j2++) r += (skeys[j2] < my);
    ssorted[r] = my;
  }
  __syncthreads();

  if (t < NSAMP) {
    int v;
    if (t < M) {
      v = (int)(ssorted[t] & 0xFFFull);
    } else {
      int s = t - M;                          // s-th smallest non-inner index
      int idx = s;
      for (int it = 0; it < 40; it++) {
        int c = 0;
        for (int j2 = 0; j2 < M; j2++) c += ((int)(skeys[j2] & 0xFFFull) <= idx);
        int nidx = s + c;
        if (nidx == idx) break;
        idx = nidx;
      }
      v = idx;
    }
    sel[t] = v;
  }
  __syncthreads();

  for (int e = t; e < NSAMP * C0; e += 256) {
    int k = e / C0;
    int cc = e - k * C0;
    int j = sel[k];
    xs0[e] = (cc < 3) ? X[j * 3 + cc] : P[j * DP + (cc - 3)];
  }
  __syncthreads();

  const int row = t >> 3, c8 = (t & 7) * 8;
  float a[8];
  #pragma unroll
  for (int j = 0; j < 8; j++) a[j] = b0s[c8 + j];
  #pragma unroll
  for (int k = 0; k < C0; k++) {
    float xv = xs0[row * C0 + k];
    #pragma unroll
    for (int j = 0; j < 8; j++) a[j] = fmaf(xv, w0s[k * 64 + c8 + j], a[j]);
  }
  float* Y = y0 + ((size_t)blk * NSAMP + row) * 64 + c8;
  *(float4*)(Y + 0) = make_float4(a[0], a[1], a[2], a[3]);
  *(float4*)(Y + 4) = make_float4(a[4], a[5], a[6], a[7]);
  #pragma unroll
  for (int j = 0; j < 8; j++) red[0][row][c8 + j] = a[j];
  #pragma unroll
  for (int j = 0; j < 8; j++) red[1][row][c8 + j] = a[j] * a[j];
  __syncthreads();
  if (t < 64) {
    float S = 0.f, Q = 0.f;
    #pragma unroll
    for (int g = 0; g < NSAMP; g++) { S += red[0][g][t]; Q += red[1][g][t]; }
    psum[(size_t)t * 8192 + blk] = S;
    psq [(size_t)t * 8192 + blk] = Q;
  }
}

// ---------------------------------------------------------------------------
// dense mid (unchanged R8)
// ---------------------------------------------------------------------------
template <int RPB, int COUT, int CGN, int NBLKS, bool MM>
__global__ __launch_bounds__(256)
void dense_mid_kernel(const float* __restrict__ yin, const float* __restrict__ ssin,
                      const float* __restrict__ W, const float* __restrict__ bias,
                      float* __restrict__ yout,
                      float* __restrict__ psum, float* __restrict__ psq,
                      float* __restrict__ gmax, float* __restrict__ gmin) {
  constexpr int NG = 256 / CGN;
  __shared__ float xs[RPB * 68];
  __shared__ float ws[64 * COUT];
  __shared__ float scs[64], shs[64];
  __shared__ float red[2][NG][COUT];
  __shared__ float redm[MM ? 2 : 1][MM ? NG : 1][MM ? COUT : 1];
  const int blk = blockIdx.x, t = threadIdx.x;
  if (t < 64) { scs[t] = ssin[t]; shs[t] = ssin[128 + t]; }
  __syncthreads();
  const size_t rbase = (size_t)blk * RPB;
  for (int e = t; e < RPB * 64; e += 256) {
    int c = e & 63;
    float v = yin[rbase * 64 + e];
    xs[(e >> 6) * 68 + c] = fmaxf(fmaf(v, scs[c], shs[c]), 0.f);
  }
  for (int e = t; e < 64 * COUT; e += 256) ws[e] = W[e];
  __syncthreads();
  const int rg = t / CGN, cg = t % CGN;
  float acc[4][4];
  float4 bv = *(const float4*)(bias + cg * 4);
  #pragma unroll
  for (int r = 0; r < 4; r++) { acc[r][0] = bv.x; acc[r][1] = bv.y; acc[r][2] = bv.z; acc[r][3] = bv.w; }
  for (int k0 = 0; k0 < 64; k0 += 4) {
    float4 xv[4];
    #pragma unroll
    for (int r = 0; r < 4; r++)
      xv[r] = *(const float4*)(xs + (rg * 4 + r) * 68 + k0);
    #pragma unroll
    for (int kk = 0; kk < 4; kk++) {
      float4 wv = *(const float4*)(ws + (k0 + kk) * COUT + cg * 4);
      #pragma unroll
      for (int r = 0; r < 4; r++) {
        float x = (&xv[r].x)[kk];
        acc[r][0] = fmaf(x, wv.x, acc[r][0]);
        acc[r][1] = fmaf(x, wv.y, acc[r][1]);
        acc[r][2] = fmaf(x, wv.z, acc[r][2]);
        acc[r][3] = fmaf(x, wv.w, acc[r][3]);
      }
    }
  }
  if constexpr (!MM) {
    #pragma unroll
    for (int r = 0; r < 4; r++)
      *(float4*)(yout + (rbase + rg * 4 + r) * COUT + cg * 4) =
          make_float4(acc[r][0], acc[r][1], acc[r][2], acc[r][3]);
  }
  #pragma unroll
  for (int c4 = 0; c4 < 4; c4++) {
    float s = 0.f, q = 0.f;
    #pragma unroll
    for (int r = 0; r < 4; r++) { float v = acc[r][c4]; s += v; q = fmaf(v, v, q); }
    red[0][rg][cg * 4 + c4] = s;
    red[1][rg][cg * 4 + c4] = q;
    if constexpr (MM) {
      float mx = acc[0][c4], mn = acc[0][c4];
      #pragma unroll
      for (int r = 1; r < 4; r++) { mx = fmaxf(mx, acc[r][c4]); mn = fminf(mn, acc[r][c4]); }
      redm[0][rg][cg * 4 + c4] = mx;
      redm[1][rg][cg * 4 + c4] = mn;
    }
  }
  __syncthreads();
  if (t < COUT) {
    float S = 0.f, Q = 0.f;
    #pragma unroll
    for (int g = 0; g < NG; g++) { S += red[0][g][t]; Q += red[1][g][t]; }
    psum[(size_t)t * NBLKS + blk] = S;
    psq [(size_t)t * NBLKS + blk] = Q;
    if constexpr (MM) {
      float mx = redm[0][0][t], mn = redm[1][0][t];
      #pragma unroll
      for (int g = 1; g < NG; g++) { mx = fmaxf(mx, redm[0][g][t]); mn = fminf(mn, redm[1][g][t]); }
      gmax[(size_t)blk * COUT + t] = mx;
      gmin[(size_t)blk * COUT + t] = mn;
    }
  }
}

// ---------------------------------------------------------------------------
// stats finalize (unchanged)
// ---------------------------------------------------------------------------
template <int NBLK>
__global__ __launch_bounds__(256)
void stats_final_kernel(const float* __restrict__ psum, const float* __restrict__ psq,
                        const float* __restrict__ g, const float* __restrict__ be,
                        float* __restrict__ ss_out) {
  const int c = blockIdx.x, t = threadIdx.x;
  float S = 0.f, Q = 0.f;
  for (int i = t; i < NBLK; i += 256) {
    S += psum[(size_t)c * NBLK + i];
    Q += psq [(size_t)c * NBLK + i];
  }
  __shared__ float sS[256], sQ[256];
  sS[t] = S; sQ[t] = Q;
  __syncthreads();
  #pragma unroll
  for (int off = 128; off; off >>= 1) {
    if (t < off) { sS[t] += sS[t + off]; sQ[t] += sQ[t + off]; }
    __syncthreads();
  }
  if (t == 0) {
    const float inv = 1.0f / 262144.0f;
    float mean = sS[0] * inv;
    float var = sQ[0] * inv - mean * mean;
    float scale = g[c] / sqrtf(var + 1e-3f);
    ss_out[c] = scale;
    ss_out[128 + c] = be[c] - mean * scale;
  }
}

// pool finalize (unchanged)
__global__ __launch_bounds__(128)
void pool_final_kernel(const float* __restrict__ gmax, const float* __restrict__ gmin,
                       const float* __restrict__ ss2, float* __restrict__ out1) {
  const int blk = blockIdx.x, c = threadIdx.x;
  const float sc = ss2[c], sh = ss2[128 + c];
  float v = (sc >= 0.f) ? gmax[(size_t)blk * C3 + c] : gmin[(size_t)blk * C3 + c];
  out1[(size_t)blk * C3 + c] = fmaxf(fmaf(v, sc, sh), 0.f);
}

extern "C" void kernel_launch(void* const* d_in, const int* in_sizes, int n_in,
                              void* d_out, int out_size, void* d_ws, size_t ws_size,
                              hipStream_t stream) {
  const float* xyz = (const float*)d_in[0];
  const float* pts = (const float*)d_in[1];
  const float* w0 = (const float*)d_in[2];
  const float* b0 = (const float*)d_in[3];
  const float* g0 = (const float*)d_in[4];
  const float* be0 = (const float*)d_in[5];
  const float* w1 = (const float*)d_in[6];
  const float* b1 = (const float*)d_in[7];
  const float* g1 = (const float*)d_in[8];
  const float* be1 = (const float*)d_in[9];
  const float* w2 = (const float*)d_in[10];
  const float* b2 = (const float*)d_in[11];
  const float* g2 = (const float*)d_in[12];
  const float* be2 = (const float*)d_in[13];

  float* out = (float*)d_out;
  float* cent = out;                       // [8,1024,3]
  float* out1 = out + (size_t)NB * NC * 3; // [8,1024,128]

  char* ws = (char*)d_ws;
  float* ssA  = (float*)(ws + OFF_SS);
  float* y0   = (float*)(ws + OFF_Y0);
  float* y1   = (float*)(ws + OFF_Y1);
  float* psum = (float*)(ws + OFF_PSUM);
  float* psq  = (float*)(ws + OFF_PSQ);
  float* gmx  = (float*)(ws + OFF_GMX);
  float* gmn  = (float*)(ws + OFF_GMN);

  fps_kernel<<<dim3(NB), dim3(512), 0, stream>>>(xyz, cent);

  ball_dense0_kernel<<<dim3(NB * NC), dim3(256), 0, stream>>>(
      xyz, pts, cent, w0, b0, y0, psum, psq);
  stats_final_kernel<8192><<<dim3(64), dim3(256), 0, stream>>>(psum, psq, g0, be0, ssA + 0 * 256);

  dense_mid_kernel<64, 64, 16, 4096, false><<<dim3(ROWS_TOT / 64), dim3(256), 0, stream>>>(
      y0, ssA + 0 * 256, w1, b1, y1, psum, psq, nullptr, nullptr);
  stats_final_kernel<4096><<<dim3(64), dim3(256), 0, stream>>>(psum, psq, g1, be1, ssA + 1 * 256);

  dense_mid_kernel<32, 128, 32, 8192, true><<<dim3(ROWS_TOT / 32), dim3(256), 0, stream>>>(
      y1, ssA + 1 * 256, w2, b2, nullptr, psum, psq, gmx, gmn);
  stats_final_kernel<8192><<<dim3(128), dim3(256), 0, stream>>>(psum, psq, g2, be2, ssA + 2 * 256);

  pool_final_kernel<<<dim3(NB * NC), dim3(128), 0, stream>>>(gmx, gmn, ssA + 2 * 256, out1);

  (void)in_sizes; (void)n_in; (void)out_size; (void)ws_size;
}

// Round 13
// 874.159 us; speedup vs baseline: 1.1577x; 1.1577x over previous
//
#include <hip/hip_runtime.h>

// Problem constants (B=8, N=4096, n_points=1024, n_samples=32, D_PTS=6, MLPS=[64,64,128])
#define NPTS  4096
#define NB    8
#define NC    1024
#define NSAMP 32
#define DP    6
#define C0    9      // 3 + D_PTS
#define C3    128
#define ROWS_TOT 262144   // NB*NC*NSAMP

// Workspace layout (bytes). Requires ws_size >= ~184 MB.
#define OFF_SS   (32ull<<10)     // 3 layers x {scale[128], shift[128]}
#define OFF_Y0   (16ull<<20)     // y0: 262144 x 64 f32 (67 MB)
#define OFF_Y1   (96ull<<20)     // y1: 262144 x 64 f32 (67 MB)
#define OFF_PSUM (168ull<<20)    // per-block channel sums   [C][NBLK]
#define OFF_PSQ  (172ull<<20)    // per-block channel sumsq  [C][NBLK]
#define OFF_GMX  (176ull<<20)    // per-centroid channel max [8192][128]
#define OFF_GMN  (180ull<<20)    // per-centroid channel min [8192][128]

typedef unsigned long long ull;

// Exact (no-FMA) squared distance to match numpy rounding; sum order ((x+y)+z).
__device__ __forceinline__ float sqdist_noc(float x, float y, float z,
                                            float cx, float cy, float cz) {
  #pragma clang fp contract(off)
  float dx = x - cx, dy = y - cy, dz = z - cz;
  return dx * dx + dy * dy + dz * dz;
}

// DPP move with old=self (masked/invalid lanes keep their value -> fmax identity)
template <int CTRL, int RM>
__device__ __forceinline__ float dpp_mov_f(float x) {
  int xi = __float_as_int(x);
  int r = __builtin_amdgcn_update_dpp(xi, xi, CTRL, RM, 0xf, false);
  return __int_as_float(r);
}

// Canonical gfx9 wave64 f32 max reduce; result valid in lane 63.
__device__ __forceinline__ float wave64_fmax(float x) {
  x = fmaxf(x, dpp_mov_f<0x111, 0xf>(x));  // row_shr:1
  x = fmaxf(x, dpp_mov_f<0x112, 0xf>(x));  // row_shr:2
  x = fmaxf(x, dpp_mov_f<0x114, 0xf>(x));  // row_shr:4
  x = fmaxf(x, dpp_mov_f<0x118, 0xf>(x));  // row_shr:8
  x = fmaxf(x, dpp_mov_f<0x142, 0xa>(x));  // row_bcast:15 -> rows 1,3
  x = fmaxf(x, dpp_mov_f<0x143, 0xc>(x));  // row_bcast:31 -> rows 2,3
  return x;
}

// ---------------------------------------------------------------------------
// FPS (exact R8/R11 kernel, measured 600 us — local optimum; R9/R10/R12
// perturbations all regressed): 256 thr / 4 waves, 16 pts/thread.
// ---------------------------------------------------------------------------
__global__ __launch_bounds__(256)
void fps_kernel(const float* __restrict__ xyz, float* __restrict__ cent) {
  const int b = blockIdx.x;
  const int t = threadIdx.x;
  const float* X = xyz + (size_t)b * NPTS * 3;
  float* OC = cent + (size_t)b * NC * 3;

  __shared__ float4 sxyz[NPTS];                 // 64 KB
  __shared__ float4 wkc[2][4];                  // per-wave (x,y,z,key), parity-dbuf
  __shared__ alignas(16) int wki[2][4];         // per-wave winner gidx
  __shared__ int sidx[NC];                      // 4 KB

  for (int p = t; p < NPTS; p += 256)
    sxyz[p] = make_float4(X[p * 3 + 0], X[p * 3 + 1], X[p * 3 + 2], 0.f);
  __syncthreads();

  float px[16], py[16], pz[16], h[16];
  #pragma unroll
  for (int i = 0; i < 16; i++) {
    float4 v = sxyz[t * 16 + i];
    px[i] = v.x; py[i] = v.y; pz[i] = v.z;
    h[i] = fmaf(v.x, v.x, fmaf(v.y, v.y, v.z * v.z));   // |p|^2
  }

  const int wv = t >> 6;
  float4 c;   // current centroid (x,y,z,*)

  auto step_body = [&](int pw_) {
    const float c2x = c.x + c.x, c2y = c.y + c.y, c2z = c.z + c.z;
    float key[16]; int idx[16];
    #pragma unroll
    for (int i = 0; i < 16; i++) {
      key[i] = fmaf(pz[i], -c2z, fmaf(py[i], -c2y, fmaf(px[i], -c2x, h[i])));
      idx[i] = i;
    }
    #pragma unroll
    for (int s = 1; s < 16; s <<= 1) {          // tree argmax, first-max ties
      #pragma unroll
      for (int i = 0; i < 16; i += 2 * s) {
        bool tk = key[i + s] > key[i];
        key[i] = tk ? key[i + s] : key[i];
        idx[i] = tk ? idx[i + s] : idx[i];
      }
    }
    const float mx = key[0];
    const int mj = idx[0];
    float4 cand = sxyz[(t << 4) + mj];          // speculative; hides under reduce
    float wm = wave64_fmax(mx);
    float smax = __int_as_float(__builtin_amdgcn_readlane(__float_as_int(wm), 63));
    if (mx == smax) {                           // winner lane(s) of this wave
      wkc[pw_][wv] = make_float4(cand.x, cand.y, cand.z, smax);
      wki[pw_][wv] = (t << 4) + mj;
    }
  };

  auto fold = [&](int pr_) -> int {
    float4 q0 = wkc[pr_][0], q1 = wkc[pr_][1];
    float4 q2 = wkc[pr_][2], q3 = wkc[pr_][3];
    const int4 ii = *(const int4*)&wki[pr_][0];
    bool g1 = q1.w > q0.w; float4 ca = g1 ? q1 : q0; int ia = g1 ? ii.y : ii.x;
    bool g3 = q3.w > q2.w; float4 cb = g3 ? q3 : q2; int ib = g3 ? ii.w : ii.z;
    bool gb = cb.w > ca.w; c = gb ? cb : ca; return gb ? ib : ia;
  };

  // ---- iteration 1: selection 0 is point 0 (seed) ----
  if (t == 0) { sidx[0] = 0; h[0] = -__builtin_inff(); }   // retire point 0
  c = sxyz[0];
  step_body(1);                                 // publish par = 1&1
  __syncthreads();

  for (int k = 2; k < NC; k++) {
    const int pr = (k - 1) & 1, pw = k & 1;
    int gidx = fold(pr);                        // selection k-1
    if (t == 0) sidx[k - 1] = gidx;
    if ((gidx >> 4) == t) {                     // retire: -INF loses everything
      int m = gidx & 15;
      #pragma unroll
      for (int i = 0; i < 16; i++)
        if (i == m) h[i] = -__builtin_inff();
    }
    step_body(pw);
    __syncthreads();
  }
  {                                             // epilogue: selection 1023
    int gidx = fold(1023 & 1);
    if (t == 0) sidx[NC - 1] = gidx;
  }
  __syncthreads();
  for (int i = t; i < NC; i += 256) {           // one-shot centroid emit
    float4 cc = sxyz[sidx[i]];
    OC[i * 3 + 0] = cc.x;
    OC[i * 3 + 1] = cc.y;
    OC[i * 3 + 2] = cc.z;
  }
}

// ---------------------------------------------------------------------------
// ball + dense0 FUSED (unchanged from R11): query_ball -> gather -> y0 + BN0
// partials; h0 never materialized.
// ---------------------------------------------------------------------------
#define BCAP 256
__global__ __launch_bounds__(256)
void ball_dense0_kernel(const float* __restrict__ xyz, const float* __restrict__ pts,
                        const float* __restrict__ cent,
                        const float* __restrict__ W0, const float* __restrict__ b0,
                        float* __restrict__ y0,
                        float* __restrict__ psum, float* __restrict__ psq) {
  const int blk = blockIdx.x;       // b*NC + c
  const int b = blk >> 10;
  const int t = threadIdx.x;
  const float* X = xyz + (size_t)b * NPTS * 3;
  const float* P = pts + (size_t)b * NPTS * DP;
  const float cx = cent[(size_t)blk * 3 + 0];
  const float cy = cent[(size_t)blk * 3 + 1];
  const float cz = cent[(size_t)blk * 3 + 2];

  __shared__ int scount;
  __shared__ ull skeys[BCAP];
  __shared__ ull ssorted[BCAP];
  __shared__ int sel[NSAMP];
  __shared__ float xs0[NSAMP * C0];
  __shared__ float w0s[C0 * 64];
  __shared__ float b0s[64];
  __shared__ float red[2][NSAMP][64];   // 16 KB
  if (t == 0) scount = 0;
  for (int e = t; e < C0 * 64; e += 256) w0s[e] = W0[e];
  if (t < 64) b0s[t] = b0[t];
  __syncthreads();

  #pragma unroll
  for (int i = 0; i < 16; i++) {
    int j = t * 16 + i;
    float sq = sqdist_noc(X[j * 3 + 0], X[j * 3 + 1], X[j * 3 + 2], cx, cy, cz);
    if (sq < 0.0017f) {                       // conservative guard
      float d = (sq > 0.f) ? sqrtf(sq) : 0.f; // exact per-reference norm
      if (d < 0.04f) {                        // strictly inside the clip value
        int pos = atomicAdd(&scount, 1);
        if (pos < BCAP)
          skeys[pos] = ((ull)(unsigned)__float_as_int(d) << 12) | (unsigned)j;
      }
    }
  }
  __syncthreads();
  const int M = min(scount, BCAP);

  if (t < M) {                                // rank-sort inner set
    ull my = skeys[t];
    int r = 0;
    for (int j2 = 0; j2 < M; j2++) r += (skeys[j2] < my);
    ssorted[r] = my;
  }
  __syncthreads();

  if (t < NSAMP) {
    int v;
    if (t < M) {
      v = (int)(ssorted[t] & 0xFFFull);
    } else {
      int s = t - M;                          // s-th smallest non-inner index
      int idx = s;
      for (int it = 0; it < 40; it++) {
        int c = 0;
        for (int j2 = 0; j2 < M; j2++) c += ((int)(skeys[j2] & 0xFFFull) <= idx);
        int nidx = s + c;
        if (nidx == idx) break;
        idx = nidx;
      }
      v = idx;
    }
    sel[t] = v;
  }
  __syncthreads();

  for (int e = t; e < NSAMP * C0; e += 256) {
    int k = e / C0;
    int cc = e - k * C0;
    int j = sel[k];
    xs0[e] = (cc < 3) ? X[j * 3 + cc] : P[j * DP + (cc - 3)];
  }
  __syncthreads();

  const int row = t >> 3, c8 = (t & 7) * 8;
  float a[8];
  #pragma unroll
  for (int j = 0; j < 8; j++) a[j] = b0s[c8 + j];
  #pragma unroll
  for (int k = 0; k < C0; k++) {
    float xv = xs0[row * C0 + k];
    #pragma unroll
    for (int j = 0; j < 8; j++) a[j] = fmaf(xv, w0s[k * 64 + c8 + j], a[j]);
  }
  float* Y = y0 + ((size_t)blk * NSAMP + row) * 64 + c8;
  *(float4*)(Y + 0) = make_float4(a[0], a[1], a[2], a[3]);
  *(float4*)(Y + 4) = make_float4(a[4], a[5], a[6], a[7]);
  #pragma unroll
  for (int j = 0; j < 8; j++) red[0][row][c8 + j] = a[j];
  #pragma unroll
  for (int j = 0; j < 8; j++) red[1][row][c8 + j] = a[j] * a[j];
  __syncthreads();
  if (t < 64) {
    float S = 0.f, Q = 0.f;
    #pragma unroll
    for (int g = 0; g < NSAMP; g++) { S += red[0][g][t]; Q += red[1][g][t]; }
    psum[(size_t)t * 8192 + blk] = S;
    psq [(size_t)t * 8192 + blk] = Q;
  }
}

// ---------------------------------------------------------------------------
// dense layer 1, LANE-PER-ROW: lane owns one row; x streamed from global with
// BN0+relu fused; weights W1[k*64+c] are WAVE-UNIFORM loads -> SMEM s_load
// (no LDS in the inner loop; FMA with SGPR operand). acc[64] in VGPRs,
// k-ascending fmaf == previous arithmetic chain (y1 bit-identical).
// Stats via per-wave LDS transpose [64][33] (conflict-free), 2 chunks;
// lanes 0..31 sum, 32..63 sumsq (branch-free fmaf select). 256 rows/block.
// ---------------------------------------------------------------------------
__global__ __launch_bounds__(256)
void dense_lane1_kernel(const float* __restrict__ y0, const float* __restrict__ ss0,
                        const float* __restrict__ W1, const float* __restrict__ b1,
                        float* __restrict__ y1,
                        float* __restrict__ psum, float* __restrict__ psq) {
  __shared__ float tr[4][64][33];     // 33.8 KB
  __shared__ float wred[2][4][64];    // 2 KB
  const int t = threadIdx.x, wid = t >> 6, lane = t & 63;
  const size_t row = (size_t)blockIdx.x * 256 + (size_t)(wid * 64 + lane);
  float acc[64];
  #pragma unroll
  for (int c = 0; c < 64; c++) acc[c] = b1[c];
  const float* Xr = y0 + row * 64;
  #pragma unroll 1
  for (int k0 = 0; k0 < 64; k0 += 4) {
    float4 xv = *(const float4*)(Xr + k0);
    #pragma unroll
    for (int kk = 0; kk < 4; kk++) {
      const int k = k0 + kk;
      float x = fmaxf(fmaf((&xv.x)[kk], ss0[k], ss0[128 + k]), 0.f);
      const float* Wk = W1 + k * 64;
      #pragma unroll
      for (int c = 0; c < 64; c++) acc[c] = fmaf(x, Wk[c], acc[c]);
    }
  }
  float* Yr = y1 + row * 64;
  #pragma unroll
  for (int c0 = 0; c0 < 64; c0 += 4)
    *(float4*)(Yr + c0) = make_float4(acc[c0], acc[c0 + 1], acc[c0 + 2], acc[c0 + 3]);
  // stats: transpose 32 channels at a time
  const int c = lane & 31;
  const bool isQ = lane >= 32;
  #pragma unroll
  for (int chunk = 0; chunk < 2; chunk++) {
    __syncthreads();
    #pragma unroll
    for (int j = 0; j < 32; j++) tr[wid][lane][j] = acc[chunk * 32 + j];
    __syncthreads();
    float A = 0.f;
    for (int r = 0; r < 64; r++) {
      float v = tr[wid][r][c];
      A = fmaf(v, isQ ? v : 1.0f, A);   // S-lane: A+v (exact); Q-lane: A+v*v
    }
    wred[isQ ? 1 : 0][wid][chunk * 32 + c] = A;
  }
  __syncthreads();
  if (t < 64) {
    float S = 0.f, Q = 0.f;
    #pragma unroll
    for (int w = 0; w < 4; w++) { S += wred[0][w][t]; Q += wred[1][w][t]; }
    psum[(size_t)t * 1024 + blockIdx.x] = S;
    psq [(size_t)t * 1024 + blockIdx.x] = Q;
  }
}

// ---------------------------------------------------------------------------
// dense layer 2, LANE-PER-ROW: x[64] in regs (BN1+relu fused on load);
// COUT=128 in two halves reusing acc[64]; no y2 materialization. Stats +
// per-centroid max/min via the same transpose (wave = 64 rows = 2 centroids;
// S-lane also tracks max, Q-lane tracks min via negated max).
// ---------------------------------------------------------------------------
__global__ __launch_bounds__(256)
void dense_lane2_kernel(const float* __restrict__ y1, const float* __restrict__ ss1,
                        const float* __restrict__ W2, const float* __restrict__ b2,
                        float* __restrict__ psum, float* __restrict__ psq,
                        float* __restrict__ gmax, float* __restrict__ gmin) {
  __shared__ float tr[4][64][33];     // 33.8 KB
  __shared__ float wred[2][4][128];   // 4 KB
  const int t = threadIdx.x, wid = t >> 6, lane = t & 63;
  const size_t row = (size_t)blockIdx.x * 256 + (size_t)(wid * 64 + lane);
  const int centA = blockIdx.x * 8 + wid * 2;   // rows 0..31 of this wave
  const int centB = centA + 1;                  // rows 32..63

  float x[64];
  const float* Xr = y1 + row * 64;
  #pragma unroll
  for (int k0 = 0; k0 < 64; k0 += 4) {
    float4 xv = *(const float4*)(Xr + k0);
    #pragma unroll
    for (int kk = 0; kk < 4; kk++)
      x[k0 + kk] = fmaxf(fmaf((&xv.x)[kk], ss1[k0 + kk], ss1[128 + k0 + kk]), 0.f);
  }

  const int c = lane & 31;
  const bool isQ = lane >= 32;
  #pragma unroll 1
  for (int half = 0; half < 2; half++) {
    float acc[64];
    #pragma unroll
    for (int cc = 0; cc < 64; cc++) acc[cc] = b2[half * 64 + cc];
    #pragma unroll 1
    for (int k = 0; k < 64; k++) {
      const float* Wk = W2 + k * C3 + half * 64;
      const float xk = x[k];
      #pragma unroll
      for (int cc = 0; cc < 64; cc++) acc[cc] = fmaf(xk, Wk[cc], acc[cc]);
    }
    #pragma unroll
    for (int chunk = 0; chunk < 2; chunk++) {
      __syncthreads();
      #pragma unroll
      for (int j = 0; j < 32; j++) tr[wid][lane][j] = acc[chunk * 32 + j];
      __syncthreads();
      const int ch = half * 64 + chunk * 32 + c;
      float A = 0.f, m1 = -__builtin_inff(), m2 = -__builtin_inff();
      for (int r = 0; r < 32; r++) {
        float v = tr[wid][r][c];
        A = fmaf(v, isQ ? v : 1.0f, A);
        m1 = fmaxf(m1, isQ ? -v : v);
      }
      for (int r = 32; r < 64; r++) {
        float v = tr[wid][r][c];
        A = fmaf(v, isQ ? v : 1.0f, A);
        m2 = fmaxf(m2, isQ ? -v : v);
      }
      wred[isQ ? 1 : 0][wid][ch] = A;
      if (!isQ) {
        gmax[(size_t)centA * C3 + ch] = m1;
        gmax[(size_t)centB * C3 + ch] = m2;
      } else {
        gmin[(size_t)centA * C3 + ch] = -m1;
        gmin[(size_t)centB * C3 + ch] = -m2;
      }
    }
  }
  __syncthreads();
  if (t < C3) {
    float S = 0.f, Q = 0.f;
    #pragma unroll
    for (int w = 0; w < 4; w++) { S += wred[0][w][t]; Q += wred[1][w][t]; }
    psum[(size_t)t * 1024 + blockIdx.x] = S;
    psq [(size_t)t * 1024 + blockIdx.x] = Q;
  }
}

// ---------------------------------------------------------------------------
// stats finalize (templated NBLK)
// ---------------------------------------------------------------------------
template <int NBLK>
__global__ __launch_bounds__(256)
void stats_final_kernel(const float* __restrict__ psum, const float* __restrict__ psq,
                        const float* __restrict__ g, const float* __restrict__ be,
                        float* __restrict__ ss_out) {
  const int c = blockIdx.x, t = threadIdx.x;
  float S = 0.f, Q = 0.f;
  for (int i = t; i < NBLK; i += 256) {
    S += psum[(size_t)c * NBLK + i];
    Q += psq [(size_t)c * NBLK + i];
  }
  __shared__ float sS[256], sQ[256];
  sS[t] = S; sQ[t] = Q;
  __syncthreads();
  #pragma unroll
  for (int off = 128; off; off >>= 1) {
    if (t < off) { sS[t] += sS[t + off]; sQ[t] += sQ[t + off]; }
    __syncthreads();
  }
  if (t == 0) {
    const float inv = 1.0f / 262144.0f;
    float mean = sS[0] * inv;
    float var = sQ[0] * inv - mean * mean;
    float scale = g[c] / sqrtf(var + 1e-3f);
    ss_out[c] = scale;
    ss_out[128 + c] = be[c] - mean * scale;
  }
}

// pool finalize (unchanged)
__global__ __launch_bounds__(128)
void pool_final_kernel(const float* __restrict__ gmax, const float* __restrict__ gmin,
                       const float* __restrict__ ss2, float* __restrict__ out1) {
  const int blk = blockIdx.x, c = threadIdx.x;
  const float sc = ss2[c], sh = ss2[128 + c];
  float v = (sc >= 0.f) ? gmax[(size_t)blk * C3 + c] : gmin[(size_t)blk * C3 + c];
  out1[(size_t)blk * C3 + c] = fmaxf(fmaf(v, sc, sh), 0.f);
}

extern "C" void kernel_launch(void* const* d_in, const int* in_sizes, int n_in,
                              void* d_out, int out_size, void* d_ws, size_t ws_size,
                              hipStream_t stream) {
  const float* xyz = (const float*)d_in[0];
  const float* pts = (const float*)d_in[1];
  const float* w0 = (const float*)d_in[2];
  const float* b0 = (const float*)d_in[3];
  const float* g0 = (const float*)d_in[4];
  const float* be0 = (const float*)d_in[5];
  const float* w1 = (const float*)d_in[6];
  const float* b1 = (const float*)d_in[7];
  const float* g1 = (const float*)d_in[8];
  const float* be1 = (const float*)d_in[9];
  const float* w2 = (const float*)d_in[10];
  const float* b2 = (const float*)d_in[11];
  const float* g2 = (const float*)d_in[12];
  const float* be2 = (const float*)d_in[13];

  float* out = (float*)d_out;
  float* cent = out;                       // [8,1024,3]
  float* out1 = out + (size_t)NB * NC * 3; // [8,1024,128]

  char* ws = (char*)d_ws;
  float* ssA  = (float*)(ws + OFF_SS);
  float* y0   = (float*)(ws + OFF_Y0);
  float* y1   = (float*)(ws + OFF_Y1);
  float* psum = (float*)(ws + OFF_PSUM);
  float* psq  = (float*)(ws + OFF_PSQ);
  float* gmx  = (float*)(ws + OFF_GMX);
  float* gmn  = (float*)(ws + OFF_GMN);

  fps_kernel<<<dim3(NB), dim3(256), 0, stream>>>(xyz, cent);

  ball_dense0_kernel<<<dim3(NB * NC), dim3(256), 0, stream>>>(
      xyz, pts, cent, w0, b0, y0, psum, psq);
  stats_final_kernel<8192><<<dim3(64), dim3(256), 0, stream>>>(psum, psq, g0, be0, ssA + 0 * 256);

  dense_lane1_kernel<<<dim3(ROWS_TOT / 256), dim3(256), 0, stream>>>(
      y0, ssA + 0 * 256, w1, b1, y1, psum, psq);
  stats_final_kernel<1024><<<dim3(64), dim3(256), 0, stream>>>(psum, psq, g1, be1, ssA + 1 * 256);

  dense_lane2_kernel<<<dim3(ROWS_TOT / 256), dim3(256), 0, stream>>>(
      y1, ssA + 1 * 256, w2, b2, psum, psq, gmx, gmn);
  stats_final_kernel<1024><<<dim3(128), dim3(256), 0, stream>>>(psum, psq, g2, be2, ssA + 2 * 256);

  pool_final_kernel<<<dim3(NB * NC), dim3(128), 0, stream>>>(gmx, gmn, ssA + 2 * 256, out1);

  (void)in_sizes; (void)n_in; (void)out_size; (void)ws_size;
}

// Round 14
// 818.312 us; speedup vs baseline: 1.2367x; 1.0682x over previous
//
#include <hip/hip_runtime.h>

// Problem constants (B=8, N=4096, n_points=1024, n_samples=32, D_PTS=6, MLPS=[64,64,128])
#define NPTS  4096
#define NB    8
#define NC    1024
#define NSAMP 32
#define DP    6
#define C0    9      // 3 + D_PTS
#define C3    128
#define ROWS_TOT 262144   // NB*NC*NSAMP

// Workspace layout (bytes). Requires ws_size >= ~184 MB.
#define OFF_SS   (32ull<<10)     // 3 layers x {scale[128], shift[128]}
#define OFF_Y0   (16ull<<20)     // y0: 262144 x 64 f32 (67 MB)
#define OFF_Y1   (96ull<<20)     // y1: 262144 x 64 f32 (67 MB)
#define OFF_PSUM (168ull<<20)    // per-block channel sums   [C][NBLK]
#define OFF_PSQ  (172ull<<20)    // per-block channel sumsq  [C][NBLK]
#define OFF_GMX  (176ull<<20)    // per-centroid channel max [8192][128]
#define OFF_GMN  (180ull<<20)    // per-centroid channel min [8192][128]

typedef unsigned long long ull;
typedef float v2f __attribute__((ext_vector_type(2)));

// Exact (no-FMA) squared distance to match numpy rounding; sum order ((x+y)+z).
__device__ __forceinline__ float sqdist_noc(float x, float y, float z,
                                            float cx, float cy, float cz) {
  #pragma clang fp contract(off)
  float dx = x - cx, dy = y - cy, dz = z - cz;
  return dx * dx + dy * dy + dz * dz;
}

// packed 2xf32 fma (v_pk_fma_f32); IEEE-identical per component to fmaf.
__device__ __forceinline__ v2f pk_fma(v2f a, v2f b, v2f c) {
#if __has_builtin(__builtin_elementwise_fma)
  return __builtin_elementwise_fma(a, b, c);
#else
  v2f r; r.x = fmaf(a.x, b.x, c.x); r.y = fmaf(a.y, b.y, c.y); return r;
#endif
}

// DPP move with old=self (masked/invalid lanes keep their value -> fmax identity)
template <int CTRL, int RM>
__device__ __forceinline__ float dpp_mov_f(float x) {
  int xi = __float_as_int(x);
  int r = __builtin_amdgcn_update_dpp(xi, xi, CTRL, RM, 0xf, false);
  return __int_as_float(r);
}

// Canonical gfx9 wave64 f32 max reduce; result valid in lane 63.
__device__ __forceinline__ float wave64_fmax(float x) {
  x = fmaxf(x, dpp_mov_f<0x111, 0xf>(x));  // row_shr:1
  x = fmaxf(x, dpp_mov_f<0x112, 0xf>(x));  // row_shr:2
  x = fmaxf(x, dpp_mov_f<0x114, 0xf>(x));  // row_shr:4
  x = fmaxf(x, dpp_mov_f<0x118, 0xf>(x));  // row_shr:8
  x = fmaxf(x, dpp_mov_f<0x142, 0xa>(x));  // row_bcast:15 -> rows 1,3
  x = fmaxf(x, dpp_mov_f<0x143, 0xc>(x));  // row_bcast:31 -> rows 2,3
  return x;
}

// ---------------------------------------------------------------------------
// FPS (R8 structure, measured local optimum; R14 issue-diet):
//  - distances via v_pk_fma_f32 (2 pts/inst, bit-exact)     [-48 cyc/step]
//  - retire scalarized: gidx -> readfirstlane SGPR; 16-way test on SALU,
//    exactly one v_cndmask on the VALU                       [-60..90 cyc/step]
// Structure unchanged: 256 thr/4 waves, 16 pts/thr, tree argmax, f32 DPP
// reduce, speculative cand read, coords+key parity exchange, 1 barrier/step.
// ---------------------------------------------------------------------------
__global__ __launch_bounds__(256)
void fps_kernel(const float* __restrict__ xyz, float* __restrict__ cent) {
  const int b = blockIdx.x;
  const int t = threadIdx.x;
  const float* X = xyz + (size_t)b * NPTS * 3;
  float* OC = cent + (size_t)b * NC * 3;

  __shared__ float4 sxyz[NPTS];                 // 64 KB
  __shared__ float4 wkc[2][4];                  // per-wave (x,y,z,key), parity-dbuf
  __shared__ alignas(16) int wki[2][4];         // per-wave winner gidx
  __shared__ int sidx[NC];                      // 4 KB

  for (int p = t; p < NPTS; p += 256)
    sxyz[p] = make_float4(X[p * 3 + 0], X[p * 3 + 1], X[p * 3 + 2], 0.f);
  __syncthreads();

  v2f px2[8], py2[8], pz2[8], h2[8];            // pairs: pt 2i -> .x, 2i+1 -> .y
  #pragma unroll
  for (int i = 0; i < 8; i++) {
    float4 a = sxyz[t * 16 + 2 * i];
    float4 bb = sxyz[t * 16 + 2 * i + 1];
    px2[i] = v2f{a.x, bb.x};
    py2[i] = v2f{a.y, bb.y};
    pz2[i] = v2f{a.z, bb.z};
    h2[i] = v2f{fmaf(a.x, a.x, fmaf(a.y, a.y, a.z * a.z)),
                fmaf(bb.x, bb.x, fmaf(bb.y, bb.y, bb.z * bb.z))};
  }

  const int wv = t >> 6;
  float4 c;   // current centroid (x,y,z,*)

  auto step_body = [&](int pw_) {
    const float c2x = c.x + c.x, c2y = c.y + c.y, c2z = c.z + c.z;
    const v2f vx = v2f{-c2x, -c2x}, vy = v2f{-c2y, -c2y}, vz = v2f{-c2z, -c2z};
    float key[16]; int idx[16];
    #pragma unroll
    for (int i = 0; i < 8; i++) {
      v2f k2 = pk_fma(pz2[i], vz, pk_fma(py2[i], vy, pk_fma(px2[i], vx, h2[i])));
      key[2 * i] = k2.x; key[2 * i + 1] = k2.y;
      idx[2 * i] = 2 * i; idx[2 * i + 1] = 2 * i + 1;
    }
    #pragma unroll
    for (int s = 1; s < 16; s <<= 1) {          // tree argmax, first-max ties
      #pragma unroll
      for (int i = 0; i < 16; i += 2 * s) {
        bool tk = key[i + s] > key[i];
        key[i] = tk ? key[i + s] : key[i];
        idx[i] = tk ? idx[i + s] : idx[i];
      }
    }
    const float mx = key[0];
    const int mj = idx[0];
    float4 cand = sxyz[(t << 4) + mj];          // speculative; hides under reduce
    float wm = wave64_fmax(mx);
    float smax = __int_as_float(__builtin_amdgcn_readlane(__float_as_int(wm), 63));
    if (mx == smax) {                           // winner lane(s) of this wave
      wkc[pw_][wv] = make_float4(cand.x, cand.y, cand.z, smax);
      wki[pw_][wv] = (t << 4) + mj;
    }
  };

  auto fold = [&](int pr_) -> int {
    float4 q0 = wkc[pr_][0], q1 = wkc[pr_][1];
    float4 q2 = wkc[pr_][2], q3 = wkc[pr_][3];
    const int4 ii = *(const int4*)&wki[pr_][0];
    bool g1 = q1.w > q0.w; float4 ca = g1 ? q1 : q0; int ia = g1 ? ii.y : ii.x;
    bool g3 = q3.w > q2.w; float4 cb = g3 ? q3 : q2; int ib = g3 ? ii.w : ii.z;
    bool gb = cb.w > ca.w; c = gb ? cb : ca; return gb ? ib : ia;
  };

  // ---- iteration 1: selection 0 is point 0 (seed; t0 owns pair 0 comp .x) ----
  if (t == 0) { sidx[0] = 0; h2[0].x = -__builtin_inff(); }
  c = sxyz[0];
  step_body(1);                                 // publish par = 1&1
  __syncthreads();

  for (int k = 2; k < NC; k++) {
    const int pr = (k - 1) & 1, pw = k & 1;
    int gidx = fold(pr);                        // selection k-1 (block-uniform)
    const int sg = __builtin_amdgcn_readfirstlane(gidx);
    if (t == 0) sidx[k - 1] = sg;
    {                                           // scalarized retire
      const int m = sg & 15;                    // SGPR -> SALU branches below
      const bool me = (t == (sg >> 4));         // one VALU cmp
      #pragma unroll
      for (int i = 0; i < 8; i++) {
        if (2 * i == m)     h2[i].x = me ? -__builtin_inff() : h2[i].x;
        if (2 * i + 1 == m) h2[i].y = me ? -__builtin_inff() : h2[i].y;
      }
    }
    step_body(pw);
    __syncthreads();
  }
  {                                             // epilogue: selection 1023
    int gidx = fold(1023 & 1);
    if (t == 0) sidx[NC - 1] = gidx;
  }
  __syncthreads();
  for (int i = t; i < NC; i += 256) {           // one-shot centroid emit
    float4 cc = sxyz[sidx[i]];
    OC[i * 3 + 0] = cc.x;
    OC[i * 3 + 1] = cc.y;
    OC[i * 3 + 2] = cc.z;
  }
}

// ---------------------------------------------------------------------------
// ball + dense0 FUSED (R11 + vectorized X scan): query_ball (exact stable-
// argsort semantics via the min(dist,0.04) quirk) -> gather -> y0 + BN0
// partials. X scan now 12x float4 loads/thread (was 48 dwords).
// ---------------------------------------------------------------------------
#define BCAP 256
__global__ __launch_bounds__(256)
void ball_dense0_kernel(const float* __restrict__ xyz, const float* __restrict__ pts,
                        const float* __restrict__ cent,
                        const float* __restrict__ W0, const float* __restrict__ b0,
                        float* __restrict__ y0,
                        float* __restrict__ psum, float* __restrict__ psq) {
  const int blk = blockIdx.x;       // b*NC + c
  const int b = blk >> 10;
  const int t = threadIdx.x;
  const float* X = xyz + (size_t)b * NPTS * 3;
  const float* P = pts + (size_t)b * NPTS * DP;
  const float cx = cent[(size_t)blk * 3 + 0];
  const float cy = cent[(size_t)blk * 3 + 1];
  const float cz = cent[(size_t)blk * 3 + 2];

  __shared__ int scount;
  __shared__ ull skeys[BCAP];
  __shared__ ull ssorted[BCAP];
  __shared__ int sel[NSAMP];
  __shared__ float xs0[NSAMP * C0];
  __shared__ float w0s[C0 * 64];
  __shared__ float b0s[64];
  __shared__ float red[2][NSAMP][64];   // 16 KB
  if (t == 0) scount = 0;
  for (int e = t; e < C0 * 64; e += 256) w0s[e] = W0[e];
  if (t < 64) b0s[t] = b0[t];
  __syncthreads();

  // vectorized scan: 16 points = 48 floats = 12 float4 (t*192 B, 16-aligned)
  {
    float4 xb[12];
    const float4* Xv = (const float4*)(X + (size_t)t * 48);
    #pragma unroll
    for (int i = 0; i < 12; i++) xb[i] = Xv[i];
    const float* xf = (const float*)xb;         // compile-time indices only
    #pragma unroll
    for (int i = 0; i < 16; i++) {
      int j = t * 16 + i;
      float sq = sqdist_noc(xf[i * 3 + 0], xf[i * 3 + 1], xf[i * 3 + 2], cx, cy, cz);
      if (sq < 0.0017f) {                       // conservative guard
        float d = (sq > 0.f) ? sqrtf(sq) : 0.f; // exact per-reference norm
        if (d < 0.04f) {                        // strictly inside the clip value
          int pos = atomicAdd(&scount, 1);
          if (pos < BCAP)
            skeys[pos] = ((ull)(unsigned)__float_as_int(d) << 12) | (unsigned)j;
        }
      }
    }
  }
  __syncthreads();
  const int M = min(scount, BCAP);

  if (t < M) {                                // rank-sort inner set
    ull my = skeys[t];
    int r = 0;
    for (int j2 = 0; j2 < M; j2++) r += (skeys[j2] < my);
    ssorted[r] = my;
  }
  __syncthreads();

  if (t < NSAMP) {
    int v;
    if (t < M) {
      v = (int)(ssorted[t] & 0xFFFull);
    } else {
      int s = t - M;                          // s-th smallest non-inner index
      int idx = s;
      for (int it = 0; it < 40; it++) {
        int c = 0;
        for (int j2 = 0; j2 < M; j2++) c += ((int)(skeys[j2] & 0xFFFull) <= idx);
        int nidx = s + c;
        if (nidx == idx) break;
        idx = nidx;
      }
      v = idx;
    }
    sel[t] = v;
  }
  __syncthreads();

  for (int e = t; e < NSAMP * C0; e += 256) {
    int k = e / C0;
    int cc = e - k * C0;
    int j = sel[k];
    xs0[e] = (cc < 3) ? X[j * 3 + cc] : P[j * DP + (cc - 3)];
  }
  __syncthreads();

  const int row = t >> 3, c8 = (t & 7) * 8;
  float a[8];
  #pragma unroll
  for (int j = 0; j < 8; j++) a[j] = b0s[c8 + j];
  #pragma unroll
  for (int k = 0; k < C0; k++) {
    float xv = xs0[row * C0 + k];
    #pragma unroll
    for (int j = 0; j < 8; j++) a[j] = fmaf(xv, w0s[k * 64 + c8 + j], a[j]);
  }
  float* Y = y0 + ((size_t)blk * NSAMP + row) * 64 + c8;
  *(float4*)(Y + 0) = make_float4(a[0], a[1], a[2], a[3]);
  *(float4*)(Y + 4) = make_float4(a[4], a[5], a[6], a[7]);
  #pragma unroll
  for (int j = 0; j < 8; j++) red[0][row][c8 + j] = a[j];
  #pragma unroll
  for (int j = 0; j < 8; j++) red[1][row][c8 + j] = a[j] * a[j];
  __syncthreads();
  if (t < 64) {
    float S = 0.f, Q = 0.f;
    #pragma unroll
    for (int g = 0; g < NSAMP; g++) { S += red[0][g][t]; Q += red[1][g][t]; }
    psum[(size_t)t * 8192 + blk] = S;
    psq [(size_t)t * 8192 + blk] = Q;
  }
}

// ---------------------------------------------------------------------------
// dense layer 1, LANE-PER-ROW (unchanged R13)
// ---------------------------------------------------------------------------
__global__ __launch_bounds__(256)
void dense_lane1_kernel(const float* __restrict__ y0, const float* __restrict__ ss0,
                        const float* __restrict__ W1, const float* __restrict__ b1,
                        float* __restrict__ y1,
                        float* __restrict__ psum, float* __restrict__ psq) {
  __shared__ float tr[4][64][33];
  __shared__ float wred[2][4][64];
  const int t = threadIdx.x, wid = t >> 6, lane = t & 63;
  const size_t row = (size_t)blockIdx.x * 256 + (size_t)(wid * 64 + lane);
  float acc[64];
  #pragma unroll
  for (int c = 0; c < 64; c++) acc[c] = b1[c];
  const float* Xr = y0 + row * 64;
  #pragma unroll 1
  for (int k0 = 0; k0 < 64; k0 += 4) {
    float4 xv = *(const float4*)(Xr + k0);
    #pragma unroll
    for (int kk = 0; kk < 4; kk++) {
      const int k = k0 + kk;
      float x = fmaxf(fmaf((&xv.x)[kk], ss0[k], ss0[128 + k]), 0.f);
      const float* Wk = W1 + k * 64;
      #pragma unroll
      for (int c = 0; c < 64; c++) acc[c] = fmaf(x, Wk[c], acc[c]);
    }
  }
  float* Yr = y1 + row * 64;
  #pragma unroll
  for (int c0 = 0; c0 < 64; c0 += 4)
    *(float4*)(Yr + c0) = make_float4(acc[c0], acc[c0 + 1], acc[c0 + 2], acc[c0 + 3]);
  const int c = lane & 31;
  const bool isQ = lane >= 32;
  #pragma unroll
  for (int chunk = 0; chunk < 2; chunk++) {
    __syncthreads();
    #pragma unroll
    for (int j = 0; j < 32; j++) tr[wid][lane][j] = acc[chunk * 32 + j];
    __syncthreads();
    float A = 0.f;
    for (int r = 0; r < 64; r++) {
      float v = tr[wid][r][c];
      A = fmaf(v, isQ ? v : 1.0f, A);
    }
    wred[isQ ? 1 : 0][wid][chunk * 32 + c] = A;
  }
  __syncthreads();
  if (t < 64) {
    float S = 0.f, Q = 0.f;
    #pragma unroll
    for (int w = 0; w < 4; w++) { S += wred[0][w][t]; Q += wred[1][w][t]; }
    psum[(size_t)t * 1024 + blockIdx.x] = S;
    psq [(size_t)t * 1024 + blockIdx.x] = Q;
  }
}

// ---------------------------------------------------------------------------
// dense layer 2, LANE-PER-ROW (unchanged R13)
// ---------------------------------------------------------------------------
__global__ __launch_bounds__(256)
void dense_lane2_kernel(const float* __restrict__ y1, const float* __restrict__ ss1,
                        const float* __restrict__ W2, const float* __restrict__ b2,
                        float* __restrict__ psum, float* __restrict__ psq,
                        float* __restrict__ gmax, float* __restrict__ gmin) {
  __shared__ float tr[4][64][33];
  __shared__ float wred[2][4][128];
  const int t = threadIdx.x, wid = t >> 6, lane = t & 63;
  const size_t row = (size_t)blockIdx.x * 256 + (size_t)(wid * 64 + lane);
  const int centA = blockIdx.x * 8 + wid * 2;
  const int centB = centA + 1;

  float x[64];
  const float* Xr = y1 + row * 64;
  #pragma unroll
  for (int k0 = 0; k0 < 64; k0 += 4) {
    float4 xv = *(const float4*)(Xr + k0);
    #pragma unroll
    for (int kk = 0; kk < 4; kk++)
      x[k0 + kk] = fmaxf(fmaf((&xv.x)[kk], ss1[k0 + kk], ss1[128 + k0 + kk]), 0.f);
  }

  const int c = lane & 31;
  const bool isQ = lane >= 32;
  #pragma unroll 1
  for (int half = 0; half < 2; half++) {
    float acc[64];
    #pragma unroll
    for (int cc = 0; cc < 64; cc++) acc[cc] = b2[half * 64 + cc];
    #pragma unroll 1
    for (int k = 0; k < 64; k++) {
      const float* Wk = W2 + k * C3 + half * 64;
      const float xk = x[k];
      #pragma unroll
      for (int cc = 0; cc < 64; cc++) acc[cc] = fmaf(xk, Wk[cc], acc[cc]);
    }
    #pragma unroll
    for (int chunk = 0; chunk < 2; chunk++) {
      __syncthreads();
      #pragma unroll
      for (int j = 0; j < 32; j++) tr[wid][lane][j] = acc[chunk * 32 + j];
      __syncthreads();
      const int ch = half * 64 + chunk * 32 + c;
      float A = 0.f, m1 = -__builtin_inff(), m2 = -__builtin_inff();
      for (int r = 0; r < 32; r++) {
        float v = tr[wid][r][c];
        A = fmaf(v, isQ ? v : 1.0f, A);
        m1 = fmaxf(m1, isQ ? -v : v);
      }
      for (int r = 32; r < 64; r++) {
        float v = tr[wid][r][c];
        A = fmaf(v, isQ ? v : 1.0f, A);
        m2 = fmaxf(m2, isQ ? -v : v);
      }
      wred[isQ ? 1 : 0][wid][ch] = A;
      if (!isQ) {
        gmax[(size_t)centA * C3 + ch] = m1;
        gmax[(size_t)centB * C3 + ch] = m2;
      } else {
        gmin[(size_t)centA * C3 + ch] = -m1;
        gmin[(size_t)centB * C3 + ch] = -m2;
      }
    }
  }
  __syncthreads();
  if (t < C3) {
    float S = 0.f, Q = 0.f;
    #pragma unroll
    for (int w = 0; w < 4; w++) { S += wred[0][w][t]; Q += wred[1][w][t]; }
    psum[(size_t)t * 1024 + blockIdx.x] = S;
    psq [(size_t)t * 1024 + blockIdx.x] = Q;
  }
}

// ---------------------------------------------------------------------------
// stats finalize (unchanged)
// ---------------------------------------------------------------------------
template <int NBLK>
__global__ __launch_bounds__(256)
void stats_final_kernel(const float* __restrict__ psum, const float* __restrict__ psq,
                        const float* __restrict__ g, const float* __restrict__ be,
                        float* __restrict__ ss_out) {
  const int c = blockIdx.x, t = threadIdx.x;
  float S = 0.f, Q = 0.f;
  for (int i = t; i < NBLK; i += 256) {
    S += psum[(size_t)c * NBLK + i];
    Q += psq [(size_t)c * NBLK + i];
  }
  __shared__ float sS[256], sQ[256];
  sS[t] = S; sQ[t] = Q;
  __syncthreads();
  #pragma unroll
  for (int off = 128; off; off >>= 1) {
    if (t < off) { sS[t] += sS[t + off]; sQ[t] += sQ[t + off]; }
    __syncthreads();
  }
  if (t == 0) {
    const float inv = 1.0f / 262144.0f;
    float mean = sS[0] * inv;
    float var = sQ[0] * inv - mean * mean;
    float scale = g[c] / sqrtf(var + 1e-3f);
    ss_out[c] = scale;
    ss_out[128 + c] = be[c] - mean * scale;
  }
}

// pool finalize (unchanged)
__global__ __launch_bounds__(128)
void pool_final_kernel(const float* __restrict__ gmax, const float* __restrict__ gmin,
                       const float* __restrict__ ss2, float* __restrict__ out1) {
  const int blk = blockIdx.x, c = threadIdx.x;
  const float sc = ss2[c], sh = ss2[128 + c];
  float v = (sc >= 0.f) ? gmax[(size_t)blk * C3 + c] : gmin[(size_t)blk * C3 + c];
  out1[(size_t)blk * C3 + c] = fmaxf(fmaf(v, sc, sh), 0.f);
}

extern "C" void kernel_launch(void* const* d_in, const int* in_sizes, int n_in,
                              void* d_out, int out_size, void* d_ws, size_t ws_size,
                              hipStream_t stream) {
  const float* xyz = (const float*)d_in[0];
  const float* pts = (const float*)d_in[1];
  const float* w0 = (const float*)d_in[2];
  const float* b0 = (const float*)d_in[3];
  const float* g0 = (const float*)d_in[4];
  const float* be0 = (const float*)d_in[5];
  const float* w1 = (const float*)d_in[6];
  const float* b1 = (const float*)d_in[7];
  const float* g1 = (const float*)d_in[8];
  const float* be1 = (const float*)d_in[9];
  const float* w2 = (const float*)d_in[10];
  const float* b2 = (const float*)d_in[11];
  const float* g2 = (const float*)d_in[12];
  const float* be2 = (const float*)d_in[13];

  float* out = (float*)d_out;
  float* cent = out;                       // [8,1024,3]
  float* out1 = out + (size_t)NB * NC * 3; // [8,1024,128]

  char* ws = (char*)d_ws;
  float* ssA  = (float*)(ws + OFF_SS);
  float* y0   = (float*)(ws + OFF_Y0);
  float* y1   = (float*)(ws + OFF_Y1);
  float* psum = (float*)(ws + OFF_PSUM);
  float* psq  = (float*)(ws + OFF_PSQ);
  float* gmx  = (float*)(ws + OFF_GMX);
  float* gmn  = (float*)(ws + OFF_GMN);

  fps_kernel<<<dim3(NB), dim3(256), 0, stream>>>(xyz, cent);

  ball_dense0_kernel<<<dim3(NB * NC), dim3(256), 0, stream>>>(
      xyz, pts, cent, w0, b0, y0, psum, psq);
  stats_final_kernel<8192><<<dim3(64), dim3(256), 0, stream>>>(psum, psq, g0, be0, ssA + 0 * 256);

  dense_lane1_kernel<<<dim3(ROWS_TOT / 256), dim3(256), 0, stream>>>(
      y0, ssA + 0 * 256, w1, b1, y1, psum, psq);
  stats_final_kernel<1024><<<dim3(64), dim3(256), 0, stream>>>(psum, psq, g1, be1, ssA + 1 * 256);

  dense_lane2_kernel<<<dim3(ROWS_TOT / 256), dim3(256), 0, stream>>>(
      y1, ssA + 1 * 256, w2, b2, psum, psq, gmx, gmn);
  stats_final_kernel<1024><<<dim3(128), dim3(256), 0, stream>>>(psum, psq, g2, be2, ssA + 2 * 256);

  pool_final_kernel<<<dim3(NB * NC), dim3(128), 0, stream>>>(gmx, gmn, ssA + 2 * 256, out1);

  (void)in_sizes; (void)n_in; (void)out_size; (void)ws_size;
}

// Round 15
// 807.247 us; speedup vs baseline: 1.2536x; 1.0137x over previous
//
#include <hip/hip_runtime.h>

// Problem constants (B=8, N=4096, n_points=1024, n_samples=32, D_PTS=6, MLPS=[64,64,128])
#define NPTS  4096
#define NB    8
#define NC    1024
#define NSAMP 32
#define DP    6
#define C0    9      // 3 + D_PTS
#define C3    128
#define ROWS_TOT 262144   // NB*NC*NSAMP

// Workspace layout (bytes). Requires ws_size >= ~184 MB.
#define OFF_SS   (32ull<<10)     // 3 layers x {scale[128], shift[128]}
#define OFF_Y0   (16ull<<20)     // y0: 262144 x 64 f32 (67 MB)
#define OFF_Y1   (96ull<<20)     // y1: 262144 x 64 f32 (67 MB)
#define OFF_PSUM (168ull<<20)    // per-block channel sums   [C][NBLK]
#define OFF_PSQ  (172ull<<20)    // per-block channel sumsq  [C][NBLK]
#define OFF_GMX  (176ull<<20)    // per-centroid channel max [8192][128]
#define OFF_GMN  (180ull<<20)    // per-centroid channel min [8192][128]

typedef unsigned long long ull;
typedef float v2f __attribute__((ext_vector_type(2)));

// Exact (no-FMA) squared distance to match numpy rounding; sum order ((x+y)+z).
__device__ __forceinline__ float sqdist_noc(float x, float y, float z,
                                            float cx, float cy, float cz) {
  #pragma clang fp contract(off)
  float dx = x - cx, dy = y - cy, dz = z - cz;
  return dx * dx + dy * dy + dz * dz;
}

// DPP move with old=self (masked/invalid lanes keep their value -> fmax identity)
template <int CTRL, int RM>
__device__ __forceinline__ float dpp_mov_f(float x) {
  int xi = __float_as_int(x);
  int r = __builtin_amdgcn_update_dpp(xi, xi, CTRL, RM, 0xf, false);
  return __int_as_float(r);
}

// Canonical gfx9 wave64 f32 max reduce; result valid in lane 63.
__device__ __forceinline__ float wave64_fmax(float x) {
  x = fmaxf(x, dpp_mov_f<0x111, 0xf>(x));  // row_shr:1
  x = fmaxf(x, dpp_mov_f<0x112, 0xf>(x));  // row_shr:2
  x = fmaxf(x, dpp_mov_f<0x114, 0xf>(x));  // row_shr:4
  x = fmaxf(x, dpp_mov_f<0x118, 0xf>(x));  // row_shr:8
  x = fmaxf(x, dpp_mov_f<0x142, 0xa>(x));  // row_bcast:15 -> rows 1,3
  x = fmaxf(x, dpp_mov_f<0x143, 0xc>(x));  // row_bcast:31 -> rows 2,3
  return x;
}

// ---------------------------------------------------------------------------
// FPS (EXACT R8/R11/R13 kernel — measured 600.4 us on three rounds; R14's
// pk_fma/scalar-retire micro-opts REGRESSED +11 us and are reverted):
// 256 thr / 4 waves, 16 pts/thread; tree argmax; f32 DPP reduce; speculative
// candidate-coord read; coords+key parity exchange; 1 barrier/step.
// ---------------------------------------------------------------------------
__global__ __launch_bounds__(256)
void fps_kernel(const float* __restrict__ xyz, float* __restrict__ cent) {
  const int b = blockIdx.x;
  const int t = threadIdx.x;
  const float* X = xyz + (size_t)b * NPTS * 3;
  float* OC = cent + (size_t)b * NC * 3;

  __shared__ float4 sxyz[NPTS];                 // 64 KB
  __shared__ float4 wkc[2][4];                  // per-wave (x,y,z,key), parity-dbuf
  __shared__ alignas(16) int wki[2][4];         // per-wave winner gidx
  __shared__ int sidx[NC];                      // 4 KB

  for (int p = t; p < NPTS; p += 256)
    sxyz[p] = make_float4(X[p * 3 + 0], X[p * 3 + 1], X[p * 3 + 2], 0.f);
  __syncthreads();

  float px[16], py[16], pz[16], h[16];
  #pragma unroll
  for (int i = 0; i < 16; i++) {
    float4 v = sxyz[t * 16 + i];
    px[i] = v.x; py[i] = v.y; pz[i] = v.z;
    h[i] = fmaf(v.x, v.x, fmaf(v.y, v.y, v.z * v.z));   // |p|^2
  }

  const int wv = t >> 6;
  float4 c;   // current centroid (x,y,z,*)

  auto step_body = [&](int pw_) {
    const float c2x = c.x + c.x, c2y = c.y + c.y, c2z = c.z + c.z;
    float key[16]; int idx[16];
    #pragma unroll
    for (int i = 0; i < 16; i++) {
      key[i] = fmaf(pz[i], -c2z, fmaf(py[i], -c2y, fmaf(px[i], -c2x, h[i])));
      idx[i] = i;
    }
    #pragma unroll
    for (int s = 1; s < 16; s <<= 1) {          // tree argmax, first-max ties
      #pragma unroll
      for (int i = 0; i < 16; i += 2 * s) {
        bool tk = key[i + s] > key[i];
        key[i] = tk ? key[i + s] : key[i];
        idx[i] = tk ? idx[i + s] : idx[i];
      }
    }
    const float mx = key[0];
    const int mj = idx[0];
    float4 cand = sxyz[(t << 4) + mj];          // speculative; hides under reduce
    float wm = wave64_fmax(mx);
    float smax = __int_as_float(__builtin_amdgcn_readlane(__float_as_int(wm), 63));
    if (mx == smax) {                           // winner lane(s) of this wave
      wkc[pw_][wv] = make_float4(cand.x, cand.y, cand.z, smax);
      wki[pw_][wv] = (t << 4) + mj;
    }
  };

  auto fold = [&](int pr_) -> int {
    float4 q0 = wkc[pr_][0], q1 = wkc[pr_][1];
    float4 q2 = wkc[pr_][2], q3 = wkc[pr_][3];
    const int4 ii = *(const int4*)&wki[pr_][0];
    bool g1 = q1.w > q0.w; float4 ca = g1 ? q1 : q0; int ia = g1 ? ii.y : ii.x;
    bool g3 = q3.w > q2.w; float4 cb = g3 ? q3 : q2; int ib = g3 ? ii.w : ii.z;
    bool gb = cb.w > ca.w; c = gb ? cb : ca; return gb ? ib : ia;
  };

  // ---- iteration 1: selection 0 is point 0 (seed) ----
  if (t == 0) { sidx[0] = 0; h[0] = -__builtin_inff(); }   // retire point 0
  c = sxyz[0];
  step_body(1);                                 // publish par = 1&1
  __syncthreads();

  for (int k = 2; k < NC; k++) {
    const int pr = (k - 1) & 1, pw = k & 1;
    int gidx = fold(pr);                        // selection k-1
    if (t == 0) sidx[k - 1] = gidx;
    if ((gidx >> 4) == t) {                     // retire: -INF loses everything
      int m = gidx & 15;
      #pragma unroll
      for (int i = 0; i < 16; i++)
        if (i == m) h[i] = -__builtin_inff();
    }
    step_body(pw);
    __syncthreads();
  }
  {                                             // epilogue: selection 1023
    int gidx = fold(1023 & 1);
    if (t == 0) sidx[NC - 1] = gidx;
  }
  __syncthreads();
  for (int i = t; i < NC; i += 256) {           // one-shot centroid emit
    float4 cc = sxyz[sidx[i]];
    OC[i * 3 + 0] = cc.x;
    OC[i * 3 + 1] = cc.y;
    OC[i * 3 + 2] = cc.z;
  }
}

// ---------------------------------------------------------------------------
// ball + dense0 FUSED: vectorized X scan (12x float4/thread, R14 win) +
// PACKED exact distances: 2 points per v2f, elementwise sub/mul/add under
// contract(off) -- per-component ops identical to sqdist_noc (same order,
// no fma) so inner/outer classification is bit-exact.
// ---------------------------------------------------------------------------
#define BCAP 256
__global__ __launch_bounds__(256)
void ball_dense0_kernel(const float* __restrict__ xyz, const float* __restrict__ pts,
                        const float* __restrict__ cent,
                        const float* __restrict__ W0, const float* __restrict__ b0,
                        float* __restrict__ y0,
                        float* __restrict__ psum, float* __restrict__ psq) {
  const int blk = blockIdx.x;       // b*NC + c
  const int b = blk >> 10;
  const int t = threadIdx.x;
  const float* X = xyz + (size_t)b * NPTS * 3;
  const float* P = pts + (size_t)b * NPTS * DP;
  const float cx = cent[(size_t)blk * 3 + 0];
  const float cy = cent[(size_t)blk * 3 + 1];
  const float cz = cent[(size_t)blk * 3 + 2];

  __shared__ int scount;
  __shared__ ull skeys[BCAP];
  __shared__ ull ssorted[BCAP];
  __shared__ int sel[NSAMP];
  __shared__ float xs0[NSAMP * C0];
  __shared__ float w0s[C0 * 64];
  __shared__ float b0s[64];
  __shared__ float red[2][NSAMP][64];   // 16 KB
  if (t == 0) scount = 0;
  for (int e = t; e < C0 * 64; e += 256) w0s[e] = W0[e];
  if (t < 64) b0s[t] = b0[t];
  __syncthreads();

  // vectorized scan: 16 points = 48 floats = 12 float4 (t*192 B, 16-aligned);
  // distances packed 2 pts/v2f, exact no-FMA per component.
  {
    float4 xb[12];
    const float4* Xv = (const float4*)(X + (size_t)t * 48);
    #pragma unroll
    for (int i = 0; i < 12; i++) xb[i] = Xv[i];
    const float* xf = (const float*)xb;         // compile-time indices only
    v2f sq2[8];
    {
      #pragma clang fp contract(off)
      const v2f c2x = v2f{cx, cx}, c2y = v2f{cy, cy}, c2z = v2f{cz, cz};
      #pragma unroll
      for (int i = 0; i < 8; i++) {             // pair = points 2i, 2i+1
        v2f x2 = v2f{xf[6 * i + 0], xf[6 * i + 3]};
        v2f y2 = v2f{xf[6 * i + 1], xf[6 * i + 4]};
        v2f z2 = v2f{xf[6 * i + 2], xf[6 * i + 5]};
        v2f dx = x2 - c2x, dy = y2 - c2y, dz = z2 - c2z;
        sq2[i] = (dx * dx + dy * dy) + dz * dz;
      }
    }
    #pragma unroll
    for (int i = 0; i < 16; i++) {
      int j = t * 16 + i;
      float sq = (i & 1) ? sq2[i >> 1].y : sq2[i >> 1].x;
      if (sq < 0.0017f) {                       // conservative guard
        float d = (sq > 0.f) ? sqrtf(sq) : 0.f; // exact per-reference norm
        if (d < 0.04f) {                        // strictly inside the clip value
          int pos = atomicAdd(&scount, 1);
          if (pos < BCAP)
            skeys[pos] = ((ull)(unsigned)__float_as_int(d) << 12) | (unsigned)j;
        }
      }
    }
  }
  __syncthreads();
  const int M = min(scount, BCAP);

  if (t < M) {                                // rank-sort inner set
    ull my = skeys[t];
    int r = 0;
    for (int j2 = 0; j2 < M; j2++) r += (skeys[j2] < my);
    ssorted[r] = my;
  }
  __syncthreads();

  if (t < NSAMP) {
    int v;
    if (t < M) {
      v = (int)(ssorted[t] & 0xFFFull);
    } else {
      int s = t - M;                          // s-th smallest non-inner index
      int idx = s;
      for (int it = 0; it < 40; it++) {
        int c = 0;
        for (int j2 = 0; j2 < M; j2++) c += ((int)(skeys[j2] & 0xFFFull) <= idx);
        int nidx = s + c;
        if (nidx == idx) break;
        idx = nidx;
      }
      v = idx;
    }
    sel[t] = v;
  }
  __syncthreads();

  for (int e = t; e < NSAMP * C0; e += 256) {
    int k = e / C0;
    int cc = e - k * C0;
    int j = sel[k];
    xs0[e] = (cc < 3) ? X[j * 3 + cc] : P[j * DP + (cc - 3)];
  }
  __syncthreads();

  const int row = t >> 3, c8 = (t & 7) * 8;
  float a[8];
  #pragma unroll
  for (int j = 0; j < 8; j++) a[j] = b0s[c8 + j];
  #pragma unroll
  for (int k = 0; k < C0; k++) {
    float xv = xs0[row * C0 + k];
    #pragma unroll
    for (int j = 0; j < 8; j++) a[j] = fmaf(xv, w0s[k * 64 + c8 + j], a[j]);
  }
  float* Y = y0 + ((size_t)blk * NSAMP + row) * 64 + c8;
  *(float4*)(Y + 0) = make_float4(a[0], a[1], a[2], a[3]);
  *(float4*)(Y + 4) = make_float4(a[4], a[5], a[6], a[7]);
  #pragma unroll
  for (int j = 0; j < 8; j++) red[0][row][c8 + j] = a[j];
  #pragma unroll
  for (int j = 0; j < 8; j++) red[1][row][c8 + j] = a[j] * a[j];
  __syncthreads();
  if (t < 64) {
    float S = 0.f, Q = 0.f;
    #pragma unroll
    for (int g = 0; g < NSAMP; g++) { S += red[0][g][t]; Q += red[1][g][t]; }
    psum[(size_t)t * 8192 + blk] = S;
    psq [(size_t)t * 8192 + blk] = Q;
  }
}

// ---------------------------------------------------------------------------
// dense layer 1, LANE-PER-ROW (unchanged R13)
// ---------------------------------------------------------------------------
__global__ __launch_bounds__(256)
void dense_lane1_kernel(const float* __restrict__ y0, const float* __restrict__ ss0,
                        const float* __restrict__ W1, const float* __restrict__ b1,
                        float* __restrict__ y1,
                        float* __restrict__ psum, float* __restrict__ psq) {
  __shared__ float tr[4][64][33];
  __shared__ float wred[2][4][64];
  const int t = threadIdx.x, wid = t >> 6, lane = t & 63;
  const size_t row = (size_t)blockIdx.x * 256 + (size_t)(wid * 64 + lane);
  float acc[64];
  #pragma unroll
  for (int c = 0; c < 64; c++) acc[c] = b1[c];
  const float* Xr = y0 + row * 64;
  #pragma unroll 1
  for (int k0 = 0; k0 < 64; k0 += 4) {
    float4 xv = *(const float4*)(Xr + k0);
    #pragma unroll
    for (int kk = 0; kk < 4; kk++) {
      const int k = k0 + kk;
      float x = fmaxf(fmaf((&xv.x)[kk], ss0[k], ss0[128 + k]), 0.f);
      const float* Wk = W1 + k * 64;
      #pragma unroll
      for (int c = 0; c < 64; c++) acc[c] = fmaf(x, Wk[c], acc[c]);
    }
  }
  float* Yr = y1 + row * 64;
  #pragma unroll
  for (int c0 = 0; c0 < 64; c0 += 4)
    *(float4*)(Yr + c0) = make_float4(acc[c0], acc[c0 + 1], acc[c0 + 2], acc[c0 + 3]);
  const int c = lane & 31;
  const bool isQ = lane >= 32;
  #pragma unroll
  for (int chunk = 0; chunk < 2; chunk++) {
    __syncthreads();
    #pragma unroll
    for (int j = 0; j < 32; j++) tr[wid][lane][j] = acc[chunk * 32 + j];
    __syncthreads();
    float A = 0.f;
    for (int r = 0; r < 64; r++) {
      float v = tr[wid][r][c];
      A = fmaf(v, isQ ? v : 1.0f, A);
    }
    wred[isQ ? 1 : 0][wid][chunk * 32 + c] = A;
  }
  __syncthreads();
  if (t < 64) {
    float S = 0.f, Q = 0.f;
    #pragma unroll
    for (int w = 0; w < 4; w++) { S += wred[0][w][t]; Q += wred[1][w][t]; }
    psum[(size_t)t * 1024 + blockIdx.x] = S;
    psq [(size_t)t * 1024 + blockIdx.x] = Q;
  }
}

// ---------------------------------------------------------------------------
// dense layer 2, LANE-PER-ROW (unchanged R13)
// ---------------------------------------------------------------------------
__global__ __launch_bounds__(256)
void dense_lane2_kernel(const float* __restrict__ y1, const float* __restrict__ ss1,
                        const float* __restrict__ W2, const float* __restrict__ b2,
                        float* __restrict__ psum, float* __restrict__ psq,
                        float* __restrict__ gmax, float* __restrict__ gmin) {
  __shared__ float tr[4][64][33];
  __shared__ float wred[2][4][128];
  const int t = threadIdx.x, wid = t >> 6, lane = t & 63;
  const size_t row = (size_t)blockIdx.x * 256 + (size_t)(wid * 64 + lane);
  const int centA = blockIdx.x * 8 + wid * 2;
  const int centB = centA + 1;

  float x[64];
  const float* Xr = y1 + row * 64;
  #pragma unroll
  for (int k0 = 0; k0 < 64; k0 += 4) {
    float4 xv = *(const float4*)(Xr + k0);
    #pragma unroll
    for (int kk = 0; kk < 4; kk++)
      x[k0 + kk] = fmaxf(fmaf((&xv.x)[kk], ss1[k0 + kk], ss1[128 + k0 + kk]), 0.f);
  }

  const int c = lane & 31;
  const bool isQ = lane >= 32;
  #pragma unroll 1
  for (int half = 0; half < 2; half++) {
    float acc[64];
    #pragma unroll
    for (int cc = 0; cc < 64; cc++) acc[cc] = b2[half * 64 + cc];
    #pragma unroll 1
    for (int k = 0; k < 64; k++) {
      const float* Wk = W2 + k * C3 + half * 64;
      const float xk = x[k];
      #pragma unroll
      for (int cc = 0; cc < 64; cc++) acc[cc] = fmaf(xk, Wk[cc], acc[cc]);
    }
    #pragma unroll
    for (int chunk = 0; chunk < 2; chunk++) {
      __syncthreads();
      #pragma unroll
      for (int j = 0; j < 32; j++) tr[wid][lane][j] = acc[chunk * 32 + j];
      __syncthreads();
      const int ch = half * 64 + chunk * 32 + c;
      float A = 0.f, m1 = -__builtin_inff(), m2 = -__builtin_inff();
      for (int r = 0; r < 32; r++) {
        float v = tr[wid][r][c];
        A = fmaf(v, isQ ? v : 1.0f, A);
        m1 = fmaxf(m1, isQ ? -v : v);
      }
      for (int r = 32; r < 64; r++) {
        float v = tr[wid][r][c];
        A = fmaf(v, isQ ? v : 1.0f, A);
        m2 = fmaxf(m2, isQ ? -v : v);
      }
      wred[isQ ? 1 : 0][wid][ch] = A;
      if (!isQ) {
        gmax[(size_t)centA * C3 + ch] = m1;
        gmax[(size_t)centB * C3 + ch] = m2;
      } else {
        gmin[(size_t)centA * C3 + ch] = -m1;
        gmin[(size_t)centB * C3 + ch] = -m2;
      }
    }
  }
  __syncthreads();
  if (t < C3) {
    float S = 0.f, Q = 0.f;
    #pragma unroll
    for (int w = 0; w < 4; w++) { S += wred[0][w][t]; Q += wred[1][w][t]; }
    psum[(size_t)t * 1024 + blockIdx.x] = S;
    psq [(size_t)t * 1024 + blockIdx.x] = Q;
  }
}

// ---------------------------------------------------------------------------
// stats finalize (unchanged)
// ---------------------------------------------------------------------------
template <int NBLK>
__global__ __launch_bounds__(256)
void stats_final_kernel(const float* __restrict__ psum, const float* __restrict__ psq,
                        const float* __restrict__ g, const float* __restrict__ be,
                        float* __restrict__ ss_out) {
  const int c = blockIdx.x, t = threadIdx.x;
  float S = 0.f, Q = 0.f;
  for (int i = t; i < NBLK; i += 256) {
    S += psum[(size_t)c * NBLK + i];
    Q += psq [(size_t)c * NBLK + i];
  }
  __shared__ float sS[256], sQ[256];
  sS[t] = S; sQ[t] = Q;
  __syncthreads();
  #pragma unroll
  for (int off = 128; off; off >>= 1) {
    if (t < off) { sS[t] += sS[t + off]; sQ[t] += sQ[t + off]; }
    __syncthreads();
  }
  if (t == 0) {
    const float inv = 1.0f / 262144.0f;
    float mean = sS[0] * inv;
    float var = sQ[0] * inv - mean * mean;
    float scale = g[c] / sqrtf(var + 1e-3f);
    ss_out[c] = scale;
    ss_out[128 + c] = be[c] - mean * scale;
  }
}

// pool finalize (unchanged)
__global__ __launch_bounds__(128)
void pool_final_kernel(const float* __restrict__ gmax, const float* __restrict__ gmin,
                       const float* __restrict__ ss2, float* __restrict__ out1) {
  const int blk = blockIdx.x, c = threadIdx.x;
  const float sc = ss2[c], sh = ss2[128 + c];
  float v = (sc >= 0.f) ? gmax[(size_t)blk * C3 + c] : gmin[(size_t)blk * C3 + c];
  out1[(size_t)blk * C3 + c] = fmaxf(fmaf(v, sc, sh), 0.f);
}

extern "C" void kernel_launch(void* const* d_in, const int* in_sizes, int n_in,
                              void* d_out, int out_size, void* d_ws, size_t ws_size,
                              hipStream_t stream) {
  const float* xyz = (const float*)d_in[0];
  const float* pts = (const float*)d_in[1];
  const float* w0 = (const float*)d_in[2];
  const float* b0 = (const float*)d_in[3];
  const float* g0 = (const float*)d_in[4];
  const float* be0 = (const float*)d_in[5];
  const float* w1 = (const float*)d_in[6];
  const float* b1 = (const float*)d_in[7];
  const float* g1 = (const float*)d_in[8];
  const float* be1 = (const float*)d_in[9];
  const float* w2 = (const float*)d_in[10];
  const float* b2 = (const float*)d_in[11];
  const float* g2 = (const float*)d_in[12];
  const float* be2 = (const float*)d_in[13];

  float* out = (float*)d_out;
  float* cent = out;                       // [8,1024,3]
  float* out1 = out + (size_t)NB * NC * 3; // [8,1024,128]

  char* ws = (char*)d_ws;
  float* ssA  = (float*)(ws + OFF_SS);
  float* y0   = (float*)(ws + OFF_Y0);
  float* y1   = (float*)(ws + OFF_Y1);
  float* psum = (float*)(ws + OFF_PSUM);
  float* psq  = (float*)(ws + OFF_PSQ);
  float* gmx  = (float*)(ws + OFF_GMX);
  float* gmn  = (float*)(ws + OFF_GMN);

  fps_kernel<<<dim3(NB), dim3(256), 0, stream>>>(xyz, cent);

  ball_dense0_kernel<<<dim3(NB * NC), dim3(256), 0, stream>>>(
      xyz, pts, cent, w0, b0, y0, psum, psq);
  stats_final_kernel<8192><<<dim3(64), dim3(256), 0, stream>>>(psum, psq, g0, be0, ssA + 0 * 256);

  dense_lane1_kernel<<<dim3(ROWS_TOT / 256), dim3(256), 0, stream>>>(
      y0, ssA + 0 * 256, w1, b1, y1, psum, psq);
  stats_final_kernel<1024><<<dim3(64), dim3(256), 0, stream>>>(psum, psq, g1, be1, ssA + 1 * 256);

  dense_lane2_kernel<<<dim3(ROWS_TOT / 256), dim3(256), 0, stream>>>(
      y1, ssA + 1 * 256, w2, b2, psum, psq, gmx, gmn);
  stats_final_kernel<1024><<<dim3(128), dim3(256), 0, stream>>>(psum, psq, g2, be2, ssA + 2 * 256);

  pool_final_kernel<<<dim3(NB * NC), dim3(128), 0, stream>>>(gmx, gmn, ssA + 2 * 256, out1);

  (void)in_sizes; (void)n_in; (void)out_size; (void)ws_size;
}